// Round 4
// baseline (8143.076 us; speedup 1.0000x reference)
//
#include <hip/hip_runtime.h>
#include <math.h>

#define BATCH 64
#define PIX   196
#define ENCD  2048
#define DECD  512
#define ATTD  512
#define EMBD  512
#define VOC   10000
#define LCAP  52
#define TSTEPS 51
#define XHDIM 3072   // emb(512) | gated awe(2048) | h(512)
#define AGDIM 2560   // att2(512) | gate(2048)

__device__ __forceinline__ float bf2f(unsigned short u) {
    union { unsigned int i; float f; } x; x.i = ((unsigned int)u) << 16; return x.f;
}
__device__ __forceinline__ unsigned short f2bf(float f) {
    union { float f; unsigned int i; } x; x.f = f;
    unsigned int r = x.i + 0x7fffu + ((x.i >> 16) & 1u);
    return (unsigned short)(r >> 16);
}

// ---------------- setup: stable descending argsort + int outputs ----------------
__global__ void k_setup(const int* caps, const int* lens,
                        int* order, int* declen,
                        float* caps_out, float* declen_out, float* order_out) {
    __shared__ int sl[64];
    __shared__ int so[64];
    int tid = threadIdx.x;
    sl[tid] = lens[tid];
    __syncthreads();
    int li = sl[tid];
    int pos = 0;
    for (int j = 0; j < 64; ++j) {
        int lj = sl[j];
        if (lj > li || (lj == li && j < tid)) pos++;
    }
    so[pos] = tid;
    __syncthreads();
    int ob = so[tid];
    order[tid] = ob;
    int dl = sl[ob] - 1;
    declen[tid] = dl;
    order_out[tid] = (float)ob;
    declen_out[tid] = (float)dl;
    for (int l = 0; l < LCAP; ++l)
        caps_out[tid * LCAP + l] = (float)caps[ob * LCAP + l];
}

// ---------------- one-time converts ----------------
__global__ void k_cvt(const float* s, unsigned short* d, int n) {
    int i = (blockIdx.x * 256 + threadIdx.x) * 4;
    if (i + 3 < n) {
        float4 v = *(const float4*)(s + i);
        ushort4 o;
        o.x = f2bf(v.x); o.y = f2bf(v.y); o.z = f2bf(v.z); o.w = f2bf(v.w);
        *(ushort4*)(d + i) = o;
    }
}

// Wag[k][j] = j<512 ? Wad[k][j] : Wfb[k][j-512]   (bf16, 512 x 2560)
__global__ void k_cvt_ag(const float* Wad, const float* Wfb, unsigned short* Wag) {
    int k = blockIdx.x, tid = threadIdx.x;
    for (int j4 = tid; j4 < AGDIM / 4; j4 += 256) {
        int j = j4 * 4;
        const float* src = (j < 512) ? (Wad + (size_t)k * 512 + j)
                                     : (Wfb + (size_t)k * 2048 + (j - 512));
        float4 v = *(const float4*)src;
        ushort4 o;
        o.x = f2bf(v.x); o.y = f2bf(v.y); o.z = f2bf(v.z); o.w = f2bf(v.w);
        *(ushort4*)(Wag + (size_t)k * AGDIM + j) = o;
    }
}

// Wcomb[j][k] = k<2560 ? Wih[j][k] : Whh[j][k-2560]   (bf16, row-major 2048x3072)
__global__ void k_cvt_comb(const float* Wih, const float* Whh, unsigned short* W) {
    int j = blockIdx.x, tid = threadIdx.x;
    for (int k = tid * 4; k < XHDIM; k += 1024) {
        const float* src = (k < 2560) ? (Wih + (size_t)j * 2560 + k)
                                      : (Whh + (size_t)j * 512 + (k - 2560));
        float4 v = *(const float4*)src;
        ushort4 o;
        o.x = f2bf(v.x); o.y = f2bf(v.y); o.z = f2bf(v.z); o.w = f2bf(v.w);
        *(ushort4*)(W + (size_t)j * XHDIM + k) = o;
    }
}

// enc_bf[b][p][c] = bf16(enc[order[b]][p][c])  (sorted order baked in)
__global__ void k_cvt_enc(const float* enc, const int* order, unsigned short* enc_bf) {
    int b = blockIdx.x, p = blockIdx.y, tid = threadIdx.x;
    const float* src = enc + ((size_t)order[b] * PIX + p) * ENCD + tid * 8;
    float4 v0 = *(const float4*)src;
    float4 v1 = *(const float4*)(src + 4);
    unsigned short o[8];
    o[0] = f2bf(v0.x); o[1] = f2bf(v0.y); o[2] = f2bf(v0.z); o[3] = f2bf(v0.w);
    o[4] = f2bf(v1.x); o[5] = f2bf(v1.y); o[6] = f2bf(v1.z); o[7] = f2bf(v1.w);
    *(uint4*)(enc_bf + ((size_t)b * PIX + p) * ENCD + tid * 8) = *(uint4*)o;
}

// ---------------- mean over pixels (sorted order) ----------------
__global__ void k_mean(const float* enc, const int* order, float* meanv) {
    int b = blockIdx.x;
    int col = blockIdx.y * 256 + threadIdx.x;
    int ob = order[b];
    const float* base = enc + (size_t)ob * PIX * ENCD + col;
    float acc = 0.f;
    for (int p = 0; p < PIX; ++p) acc += base[(size_t)p * ENCD];
    meanv[b * ENCD + col] = acc * (1.0f / (float)PIX);
}

// ---------------- h0/c0 tiled GEMM; h path also seeds xh h-slot ----------------
__global__ __launch_bounds__(256) void k_h0c0(const float* meanv,
                                              const float* WH, const float* bH,
                                              const float* WC, const float* bC,
                                              float* h, float* c, unsigned short* xh) {
    __shared__ float As[64 * 33];
    __shared__ float Bs[32 * 65];
    int nt = blockIdx.x, tid = threadIdx.x;
    const float* W; const float* bias; float* out; int j0; bool isH;
    if (nt < 8) { W = WH; bias = bH; out = h; j0 = nt * 64; isH = true; }
    else        { W = WC; bias = bC; out = c; j0 = (nt - 8) * 64; isH = false; }
    float acc[4][4] = {};
    int tr = tid & 15, tc = tid >> 4;
    for (int k0 = 0; k0 < ENCD; k0 += 32) {
        for (int idx = tid; idx < 512; idx += 256) {
            int rl = idx >> 3, k4 = (idx & 7) << 2;
            float4 v = *(const float4*)(meanv + (size_t)rl * ENCD + k0 + k4);
            float* d = As + rl * 33 + k4;
            d[0] = v.x; d[1] = v.y; d[2] = v.z; d[3] = v.w;
        }
        for (int idx = tid; idx < 512; idx += 256) {
            int k = idx >> 4, j4 = (idx & 15) << 2;
            float4 v = *(const float4*)(W + (size_t)(k0 + k) * DECD + j0 + j4);
            float* d = Bs + k * 65 + j4;
            d[0] = v.x; d[1] = v.y; d[2] = v.z; d[3] = v.w;
        }
        __syncthreads();
        for (int kk = 0; kk < 32; ++kk) {
            float a[4], bb[4];
            for (int i = 0; i < 4; ++i) a[i] = As[(tr * 4 + i) * 33 + kk];
            for (int i = 0; i < 4; ++i) bb[i] = Bs[kk * 65 + tc * 4 + i];
            for (int i = 0; i < 4; ++i)
                for (int j2 = 0; j2 < 4; ++j2) acc[i][j2] += a[i] * bb[j2];
        }
        __syncthreads();
    }
    for (int i = 0; i < 4; ++i)
        for (int j2 = 0; j2 < 4; ++j2) {
            int r = tr * 4 + i, j = j0 + tc * 4 + j2;
            float v = acc[i][j2] + bias[j];
            out[r * DECD + j] = v;
            if (isH) xh[(size_t)r * XHDIM + 2560 + j] = f2bf(v);
        }
}

// ---------------- att1 = enc_sorted @ att_enc_W + b -> bf16 ----------------
__global__ __launch_bounds__(256) void k_att1(const float* enc, const int* order,
                                              const float* W, const float* bias,
                                              unsigned short* att1bf) {
    __shared__ float As[64][33];
    __shared__ float Bs[32][65];
    __shared__ int rbase[64];
    int rt = blockIdx.x, ct = blockIdx.y, tid = threadIdx.x;
    int a0 = ct * 64;
    if (tid < 64) {
        int r = rt * 64 + tid;
        int b = r / PIX, p = r % PIX;
        rbase[tid] = (order[b] * PIX + p) * ENCD;
    }
    __syncthreads();
    float acc[4][4] = {};
    int tr = tid % 16, tc = tid / 16;
    for (int k0 = 0; k0 < ENCD; k0 += 32) {
        for (int idx = tid; idx < 512; idx += 256) {
            int rl = idx / 8, k4 = (idx % 8) * 4;
            float4 v = *(const float4*)(enc + (size_t)rbase[rl] + k0 + k4);
            As[rl][k4] = v.x; As[rl][k4 + 1] = v.y; As[rl][k4 + 2] = v.z; As[rl][k4 + 3] = v.w;
        }
        for (int idx = tid; idx < 512; idx += 256) {
            int k = idx / 16, a4 = (idx % 16) * 4;
            float4 v = *(const float4*)(W + (size_t)(k0 + k) * ATTD + a0 + a4);
            Bs[k][a4] = v.x; Bs[k][a4 + 1] = v.y; Bs[k][a4 + 2] = v.z; Bs[k][a4 + 3] = v.w;
        }
        __syncthreads();
        for (int kk = 0; kk < 32; ++kk) {
            float a[4], bb[4];
            for (int i = 0; i < 4; ++i) a[i] = As[tr * 4 + i][kk];
            for (int i = 0; i < 4; ++i) bb[i] = Bs[kk][tc * 4 + i];
            for (int i = 0; i < 4; ++i)
                for (int j2 = 0; j2 < 4; ++j2) acc[i][j2] += a[i] * bb[j2];
        }
        __syncthreads();
    }
    int r0 = rt * 64;
    for (int i = 0; i < 4; ++i)
        for (int j2 = 0; j2 < 4; ++j2) {
            int r = r0 + tr * 4 + i, a = a0 + tc * 4 + j2;
            att1bf[(size_t)r * ATTD + a] = f2bf(acc[i][j2] + bias[a]);
        }
}

// ---------------- K1: fused [LSTM update of step t-1] + att2/gate GEMV + emb ----------------
// grid (10, 8), block 256. Block (jt,bg): batches bg*8..+8, output cols jt*256..+256.
__global__ __launch_bounds__(256) void k_step1(
    const float* hprev, const float* cprev, float* hcur, float* ccur,
    const float* partial, const float* bih, const float* bhh, const int* declen,
    const unsigned short* Wag, const float* bad, const float* bfb,
    const float* embW, const int* caps, const int* order,
    float* att2, float* gate, unsigned short* xh, float* hall, int t) {
    __shared__ float Hs[8][512];
    int jt = blockIdx.x, bg = blockIdx.y, tid = threadIdx.x;

    if (t == 0) {
        for (int i = tid; i < 4096; i += 256) {
            int bl = i >> 9, d = i & 511;
            Hs[bl][d] = hprev[(bg * 8 + bl) * DECD + d];
        }
    } else {
        for (int i = tid; i < 4096; i += 256) {
            int bl = i >> 9, d = i & 511;
            int b = bg * 8 + bl;
            float g4[4];
            for (int q = 0; q < 4; ++q) {
                int j = q * 512 + d;
                float acc = bih[j] + bhh[j];
                for (int kc = 0; kc < 6; ++kc)
                    acc += partial[(size_t)kc * 131072 + b * 2048 + j];
                g4[q] = acc;
            }
            float si = 1.f / (1.f + expf(-g4[0]));
            float sf = 1.f / (1.f + expf(-g4[1]));
            float gg = tanhf(g4[2]);
            float so = 1.f / (1.f + expf(-g4[3]));
            float c_old = cprev[b * DECD + d];
            float c_new = sf * c_old + si * gg;
            float h_new = so * tanhf(c_new);
            bool mask = (t - 1) < declen[b];
            float h_keep = mask ? h_new : hprev[b * DECD + d];
            float c_keep = mask ? c_new : c_old;
            Hs[bl][d] = h_keep;
            if (jt == 0) {
                hcur[b * DECD + d] = h_keep;
                ccur[b * DECD + d] = c_keep;
                xh[(size_t)b * XHDIM + 2560 + d] = f2bf(h_keep);
                hall[((size_t)(t - 1) * 64 + b) * DECD + d] = h_new;
            }
        }
    }
    __syncthreads();

    // GEMV: col j = jt*256+tid over combined [att2(512) | gate(2048)]
    int j = jt * 256 + tid;
    const unsigned short* Wp = Wag + j;
    float acc[8] = {};
    for (int k = 0; k < 512; k += 4) {
        float w0 = bf2f(Wp[(size_t)(k + 0) * AGDIM]);
        float w1 = bf2f(Wp[(size_t)(k + 1) * AGDIM]);
        float w2 = bf2f(Wp[(size_t)(k + 2) * AGDIM]);
        float w3 = bf2f(Wp[(size_t)(k + 3) * AGDIM]);
        for (int bb = 0; bb < 8; ++bb) {
            float4 hv = *(const float4*)&Hs[bb][k];
            acc[bb] += w0 * hv.x + w1 * hv.y + w2 * hv.z + w3 * hv.w;
        }
    }
    if (j < 512) {
        float bv = bad[j];
        for (int bb = 0; bb < 8; ++bb)
            att2[(bg * 8 + bb) * ATTD + j] = acc[bb] + bv;
    } else {
        int jj = j - 512;
        float bv = bfb[jj];
        for (int bb = 0; bb < 8; ++bb)
            gate[(bg * 8 + bb) * ENCD + jj] = 1.f / (1.f + expf(-(acc[bb] + bv)));
    }
    // emb -> xh[0..511]
    if (jt == 0) {
        for (int bb = 0; bb < 8; ++bb) {
            int b = bg * 8 + bb;
            int tok = caps[order[b] * LCAP + t];
            for (int idx = tid; idx < EMBD; idx += 256)
                xh[(size_t)b * XHDIM + idx] = f2bf(embW[(size_t)tok * EMBD + idx]);
        }
    }
}

// ---------------- K2: fused e + softmax + awe + gated-x. grid 64, block 1024 ----------------
__global__ __launch_bounds__(1024) void k_step2(
    const unsigned short* att1bf, const float* att2,
    const float* wfull, const float* bfull,
    const unsigned short* enc_bf, const float* gate, const int* declen,
    unsigned short* xh, float* alphas_out, int t) {
    __shared__ float a2s[512];
    __shared__ float wfs[512];
    __shared__ float sal[256];
    __shared__ float sred[256];
    __shared__ float sacc[4][2048];
    int b = blockIdx.x, tid = threadIdx.x;

    if (tid < 512) { a2s[tid] = att2[b * ATTD + tid]; wfs[tid] = wfull[tid]; }
    __syncthreads();

    // e phase: wave wv handles p = wv, wv+16, ...
    int wv = tid >> 6, lane = tid & 63;
    for (int p = wv; p < PIX; p += 16) {
        uint4 v = *(const uint4*)(att1bf + ((size_t)b * PIX + p) * ATTD + lane * 8);
        const unsigned short* us = (const unsigned short*)&v;
        float acc = 0.f;
        for (int jj = 0; jj < 8; ++jj) {
            int a = lane * 8 + jj;
            float x = bf2f(us[jj]) + a2s[a];
            acc += fmaxf(x, 0.f) * wfs[a];
        }
        for (int off = 32; off; off >>= 1) acc += __shfl_down(acc, off);
        if (lane == 0) sal[p] = acc;
    }
    __syncthreads();

    // softmax over 196 (first 256 threads hold values; all threads hit barriers)
    float ev = -1e30f;
    if (tid < 256) { ev = (tid < PIX) ? sal[tid] + bfull[0] : -1e30f; sred[tid] = ev; }
    __syncthreads();
    for (int s = 128; s; s >>= 1) { if (tid < s) sred[tid] = fmaxf(sred[tid], sred[tid + s]); __syncthreads(); }
    float m = sred[0]; __syncthreads();
    float pv = 0.f;
    if (tid < 256) { pv = (tid < PIX) ? expf(ev - m) : 0.f; sred[tid] = pv; }
    __syncthreads();
    for (int s = 128; s; s >>= 1) { if (tid < s) sred[tid] += sred[tid + s]; __syncthreads(); }
    float inv = 1.f / sred[0];
    __syncthreads();
    if (tid < PIX) {
        float al = pv * inv;
        sal[tid] = al;
        bool mask = t < declen[b];
        alphas_out[((size_t)b * TSTEPS + t) * PIX + tid] = mask ? al : 0.f;
    }
    __syncthreads();

    // awe: 4 p-groups x 256 col-groups (8 cols each)
    int pg = tid >> 8, cg = tid & 255;
    float acc8[8] = {};
    const unsigned short* base = enc_bf + (size_t)b * PIX * ENCD + cg * 8;
    for (int p = pg; p < PIX; p += 4) {
        uint4 v = *(const uint4*)(base + (size_t)p * ENCD);
        const unsigned short* us = (const unsigned short*)&v;
        float a = sal[p];
        for (int jj = 0; jj < 8; ++jj) acc8[jj] += a * bf2f(us[jj]);
    }
    for (int jj = 0; jj < 8; ++jj) sacc[pg][cg * 8 + jj] = acc8[jj];
    __syncthreads();

    // final reduce + gate + write xh (2 cols/thread)
    int col = tid * 2;
    float s0 = sacc[0][col] + sacc[1][col] + sacc[2][col] + sacc[3][col];
    float s1 = sacc[0][col + 1] + sacc[1][col + 1] + sacc[2][col + 1] + sacc[3][col + 1];
    float2 gv = *(const float2*)(gate + b * ENCD + col);
    unsigned int out = (unsigned int)f2bf(gv.x * s0) | ((unsigned int)f2bf(gv.y * s1) << 16);
    *(unsigned int*)(xh + (size_t)b * XHDIM + EMBD + col) = out;
}

// ---------------- K3: gates partial GEMM (bf16): partial[kc] = xh_chunk @ Wcomb_chunk^T ----------------
__global__ __launch_bounds__(256) void k_gates(const unsigned short* xh,
                                               const unsigned short* W,
                                               float* partial) {
    __shared__ float As[64 * 33];
    __shared__ float Bs[32 * 65];
    int jt = blockIdx.x, kc = blockIdx.y, tid = threadIdx.x;
    int j0 = jt * 64, kg = kc * 512;
    float acc[4][4] = {};
    int tr = tid & 15, tc = tid >> 4;
    for (int k0 = 0; k0 < 512; k0 += 32) {
        int kb = kg + k0;
        {
            int rl = tid >> 2, k8 = (tid & 3) * 8;
            uint4 v = *(const uint4*)(xh + (size_t)rl * XHDIM + kb + k8);
            const unsigned short* us = (const unsigned short*)&v;
            float* d = As + rl * 33 + k8;
            for (int jj = 0; jj < 8; ++jj) d[jj] = bf2f(us[jj]);
        }
        {
            int jl = tid >> 2, k8 = (tid & 3) * 8;
            uint4 v = *(const uint4*)(W + (size_t)(j0 + jl) * XHDIM + kb + k8);
            const unsigned short* us = (const unsigned short*)&v;
            for (int jj = 0; jj < 8; ++jj) Bs[(k8 + jj) * 65 + jl] = bf2f(us[jj]);
        }
        __syncthreads();
        for (int kk = 0; kk < 32; ++kk) {
            float a[4], bb[4];
            for (int i2 = 0; i2 < 4; ++i2) a[i2] = As[(tr * 4 + i2) * 33 + kk];
            for (int i2 = 0; i2 < 4; ++i2) bb[i2] = Bs[kk * 65 + tc * 4 + i2];
            for (int i2 = 0; i2 < 4; ++i2)
                for (int j2 = 0; j2 < 4; ++j2) acc[i2][j2] += a[i2] * bb[j2];
        }
        __syncthreads();
    }
    float* out = partial + (size_t)kc * (64 * 2048);
    for (int i2 = 0; i2 < 4; ++i2)
        for (int j2 = 0; j2 < 4; ++j2)
            out[(tr * 4 + i2) * 2048 + j0 + tc * 4 + j2] = acc[i2][j2];
}

// ---------------- tail: hall[50] = h_new from last partials ----------------
__global__ void k_tail(const float* partial, const float* bih, const float* bhh,
                       const float* cprev, float* hall) {
    int b = blockIdx.x, d = threadIdx.x;
    float g4[4];
    for (int q = 0; q < 4; ++q) {
        int j = q * 512 + d;
        float acc = bih[j] + bhh[j];
        for (int kc = 0; kc < 6; ++kc) acc += partial[(size_t)kc * 131072 + b * 2048 + j];
        g4[q] = acc;
    }
    float si = 1.f / (1.f + expf(-g4[0]));
    float sf = 1.f / (1.f + expf(-g4[1]));
    float gg = tanhf(g4[2]);
    float so = 1.f / (1.f + expf(-g4[3]));
    float c_new = sf * cprev[b * DECD + d] + si * gg;
    float h_new = so * tanhf(c_new);
    hall[((size_t)(TSTEPS - 1) * 64 + b) * DECD + d] = h_new;
}

// ---------------- batched fc (bf16 W): preds = mask ? hall@fc_W + fc_b : 0 ----------------
__global__ __launch_bounds__(256) void k_fc(const float* hall, const unsigned short* Wbf,
                                            const float* bias, const int* declen,
                                            float* preds) {
    __shared__ float As[64][33];
    __shared__ float Bs[32][65];
    int vt = blockIdx.x, tt = blockIdx.y, tid = threadIdx.x;
    int v0 = vt * 64;
    const float* A = hall + (size_t)tt * 64 * DECD;
    float acc[4][4] = {};
    int tr = tid % 16, tc = tid / 16;
    for (int k0 = 0; k0 < DECD; k0 += 32) {
        for (int idx = tid; idx < 512; idx += 256) {
            int rl = idx / 8, k4 = (idx % 8) * 4;
            float4 v = *(const float4*)(A + (size_t)rl * DECD + k0 + k4);
            As[rl][k4] = v.x; As[rl][k4 + 1] = v.y; As[rl][k4 + 2] = v.z; As[rl][k4 + 3] = v.w;
        }
        for (int idx = tid; idx < 512; idx += 256) {
            int k = idx / 16, v4 = (idx % 16) * 4;
            float vals[4] = {0.f, 0.f, 0.f, 0.f};
            if (v0 + v4 + 3 < VOC) {
                ushort4 u = *(const ushort4*)(Wbf + (size_t)(k0 + k) * VOC + v0 + v4);
                vals[0] = bf2f(u.x); vals[1] = bf2f(u.y); vals[2] = bf2f(u.z); vals[3] = bf2f(u.w);
            }
            Bs[k][v4] = vals[0]; Bs[k][v4 + 1] = vals[1]; Bs[k][v4 + 2] = vals[2]; Bs[k][v4 + 3] = vals[3];
        }
        __syncthreads();
        for (int kk = 0; kk < 32; ++kk) {
            float a[4], bb[4];
            for (int i = 0; i < 4; ++i) a[i] = As[tr * 4 + i][kk];
            for (int i = 0; i < 4; ++i) bb[i] = Bs[kk][tc * 4 + i];
            for (int i = 0; i < 4; ++i)
                for (int j2 = 0; j2 < 4; ++j2) acc[i][j2] += a[i] * bb[j2];
        }
        __syncthreads();
    }
    for (int i = 0; i < 4; ++i) {
        int b = tr * 4 + i;
        bool mask = tt < declen[b];
        for (int j2 = 0; j2 < 4; ++j2) {
            int v = v0 + tc * 4 + j2;
            if (v < VOC)
                preds[((size_t)b * TSTEPS + tt) * VOC + v] = mask ? (acc[i][j2] + bias[v]) : 0.f;
        }
    }
}

extern "C" void kernel_launch(void* const* d_in, const int* in_sizes, int n_in,
                              void* d_out, int out_size, void* d_ws, size_t ws_size,
                              hipStream_t stream) {
    const float* enc      = (const float*)d_in[0];
    const int*   caps     = (const int*)d_in[1];
    const int*   lens     = (const int*)d_in[2];
    const float* embW     = (const float*)d_in[3];
    const float* att_enc_W = (const float*)d_in[4];
    const float* att_enc_b = (const float*)d_in[5];
    const float* att_dec_W = (const float*)d_in[6];
    const float* att_dec_b = (const float*)d_in[7];
    const float* att_full_w = (const float*)d_in[8];
    const float* att_full_b = (const float*)d_in[9];
    const float* lstm_Wih = (const float*)d_in[10];
    const float* lstm_Whh = (const float*)d_in[11];
    const float* lstm_bih = (const float*)d_in[12];
    const float* lstm_bhh = (const float*)d_in[13];
    const float* initH_W  = (const float*)d_in[14];
    const float* initH_b  = (const float*)d_in[15];
    const float* initC_W  = (const float*)d_in[16];
    const float* initC_b  = (const float*)d_in[17];
    const float* fbeta_W  = (const float*)d_in[18];
    const float* fbeta_b  = (const float*)d_in[19];
    const float* fc_W     = (const float*)d_in[20];
    const float* fc_b     = (const float*)d_in[21];

    // outputs (flat f32): preds | caps | dec_len | alphas | order
    float* o = (float*)d_out;
    float* preds_out  = o;
    float* caps_out   = o + (size_t)BATCH * TSTEPS * VOC;
    float* declen_out = caps_out + (size_t)BATCH * LCAP;
    float* order_out  = declen_out + BATCH;
    float* alphas_out = order_out + BATCH;

    // workspace layout
    char* wsb = (char*)d_ws;
    int* i_order  = (int*)wsb;
    int* i_declen = i_order + 64;
    float* f = (float*)(wsb + 512);
    float* f_mean  = f;  f += (size_t)BATCH * ENCD;
    float* f_hb0   = f;  f += (size_t)BATCH * DECD;
    float* f_hb1   = f;  f += (size_t)BATCH * DECD;
    float* f_cb0   = f;  f += (size_t)BATCH * DECD;
    float* f_cb1   = f;  f += (size_t)BATCH * DECD;
    float* f_att2  = f;  f += (size_t)BATCH * ATTD;
    float* f_gate  = f;  f += (size_t)BATCH * ENCD;
    f = (float*)(((uintptr_t)f + 255) & ~(uintptr_t)255);
    float* f_part  = f;  f += (size_t)6 * BATCH * 2048;
    float* f_hall  = f;  f += (size_t)TSTEPS * BATCH * DECD;
    f = (float*)(((uintptr_t)f + 255) & ~(uintptr_t)255);
    unsigned short* bf = (unsigned short*)f;
    unsigned short* xh_bf   = bf;  bf += (size_t)BATCH * XHDIM;
    unsigned short* att1_bf = bf;  bf += (size_t)BATCH * PIX * ATTD;
    unsigned short* Wag_bf  = bf;  bf += (size_t)DECD * AGDIM;
    unsigned short* Wcomb_bf = bf; bf += (size_t)2048 * XHDIM;
    unsigned short* Wfc_bf  = bf;  bf += (size_t)DECD * VOC;
    bf = (unsigned short*)(((uintptr_t)bf + 255) & ~(uintptr_t)255);
    unsigned short* enc_bf  = bf;  bf += (size_t)BATCH * PIX * ENCD;

    float* hbufs[2] = { f_hb0, f_hb1 };
    float* cbufs[2] = { f_cb0, f_cb1 };

    // ---- one-time setup ----
    k_setup<<<1, 64, 0, stream>>>(caps, lens, i_order, i_declen,
                                  caps_out, declen_out, order_out);
    k_cvt_ag<<<512, 256, 0, stream>>>(att_dec_W, fbeta_W, Wag_bf);
    k_cvt<<<(DECD * VOC) / 1024 + 1, 256, 0, stream>>>(fc_W, Wfc_bf, DECD * VOC);
    k_cvt_comb<<<2048, 256, 0, stream>>>(lstm_Wih, lstm_Whh, Wcomb_bf);
    k_cvt_enc<<<dim3(BATCH, PIX), 256, 0, stream>>>(enc, i_order, enc_bf);
    k_mean<<<dim3(BATCH, ENCD / 256), 256, 0, stream>>>(enc, i_order, f_mean);
    k_h0c0<<<16, 256, 0, stream>>>(f_mean, initH_W, initH_b, initC_W, initC_b,
                                   hbufs[0], cbufs[0], xh_bf);
    k_att1<<<dim3(196, 8), 256, 0, stream>>>(enc, i_order, att_enc_W, att_enc_b,
                                             att1_bf);

    // ---- recurrence: 3 nodes/step ----
    for (int t = 0; t < TSTEPS; ++t) {
        const float* hp = hbufs[(t == 0) ? 0 : ((t - 1) & 1)];
        const float* cp = cbufs[(t == 0) ? 0 : ((t - 1) & 1)];
        float* hc = hbufs[t & 1];
        float* cc = cbufs[t & 1];
        k_step1<<<dim3(10, 8), 256, 0, stream>>>(hp, cp, hc, cc, f_part,
                                                 lstm_bih, lstm_bhh, i_declen,
                                                 Wag_bf, att_dec_b, fbeta_b,
                                                 embW, caps, i_order,
                                                 f_att2, f_gate, xh_bf, f_hall, t);
        k_step2<<<64, 1024, 0, stream>>>(att1_bf, f_att2, att_full_w, att_full_b,
                                         enc_bf, f_gate, i_declen,
                                         xh_bf, alphas_out, t);
        k_gates<<<dim3(32, 6), 256, 0, stream>>>(xh_bf, Wcomb_bf, f_part);
    }
    k_tail<<<64, 512, 0, stream>>>(f_part, lstm_bih, lstm_bhh,
                                   cbufs[(TSTEPS - 1) & 1], f_hall);

    k_fc<<<dim3((VOC + 63) / 64, TSTEPS), 256, 0, stream>>>(f_hall, Wfc_bf, fc_b,
                                                            i_declen, preds_out);
}